// Round 1
// 1595.976 us; speedup vs baseline: 1.0036x; 1.0036x over previous
//
#include <hip/hip_runtime.h>
#include <hip/hip_bf16.h>
#include <vector>
#include <algorithm>
#include <cstring>
#include <cstdint>

#define NN 50000
#define EE 800000

#define CHUNKS 128
#define CHUNK_E (EE / CHUNKS)   /* 6250 edges per chunk */
#define PAIRS (NN / 2)          /* 25000 packed dst-pairs */
#define HALF (NN / 2)           /* 25000 dsts per half-range */
#define HPAIRS (HALF / 2)       /* 12500 packed pairs per half (50KB LDS) */

// ---------------- host: JAX threefry2x32 + permutation(key(42), N) ----------------
// Computed ONCE at library load time (namespace-scope initializer) so that
// kernel_launch does identical work on every call (graph-capture parity).
static inline uint32_t rotl32(uint32_t v, int r) { return (v << r) | (v >> (32 - r)); }

static inline void tf2x32(uint32_t k0, uint32_t k1, uint32_t& x0, uint32_t& x1) {
  uint32_t ks0 = k0, ks1 = k1, ks2 = k0 ^ k1 ^ 0x1BD11BDAu;
  const int r1[4] = {13, 15, 26, 6}, r2[4] = {17, 29, 16, 24};
  x0 += ks0; x1 += ks1;
  for (int i = 0; i < 4; i++) { x0 += x1; x1 = rotl32(x1, r1[i]); x1 ^= x0; }
  x0 += ks1; x1 += ks2 + 1u;
  for (int i = 0; i < 4; i++) { x0 += x1; x1 = rotl32(x1, r2[i]); x1 ^= x0; }
  x0 += ks2; x1 += ks0 + 2u;
  for (int i = 0; i < 4; i++) { x0 += x1; x1 = rotl32(x1, r1[i]); x1 ^= x0; }
  x0 += ks0; x1 += ks1 + 3u;
  for (int i = 0; i < 4; i++) { x0 += x1; x1 = rotl32(x1, r2[i]); x1 ^= x0; }
  x0 += ks1; x1 += ks2 + 4u;
  for (int i = 0; i < 4; i++) { x0 += x1; x1 = rotl32(x1, r1[i]); x1 ^= x0; }
  x0 += ks2; x1 += ks0 + 5u;
}

static void compute_perm(int* perm, int n) {
  std::vector<uint32_t> sk(n);
  std::vector<int> val(n), order(n), nv(n);
  for (int i = 0; i < n; i++) val[i] = i;
  uint32_t k0 = 0u, k1 = 42u;  // threefry_seed(42)
  for (int round = 0; round < 2; ++round) {  // 2 rounds for n=50000
    uint32_t nk0, nk1, sk0, sk1;
    { uint32_t a = 0, b = 0; tf2x32(k0, k1, a, b); nk0 = a; nk1 = b; }
    { uint32_t a = 0, b = 1; tf2x32(k0, k1, a, b); sk0 = a; sk1 = b; }
    for (int i = 0; i < n; i++) {
      uint32_t a = 0, b = (uint32_t)i;
      tf2x32(sk0, sk1, a, b);
      sk[i] = a ^ b;
    }
    for (int i = 0; i < n; i++) order[i] = i;
    std::stable_sort(order.begin(), order.end(),
                     [&](int x, int y) { return sk[x] < sk[y]; });
    for (int i = 0; i < n; i++) nv[i] = val[order[i]];
    val.swap(nv);
    k0 = nk0; k1 = nk1;
  }
  std::memcpy(perm, val.data(), (size_t)n * sizeof(int));
}

struct PermHolder {
  int perm[NN];
  PermHolder() { compute_perm(perm, NN); }
};
static const PermHolder g_perm;  // built at dlopen time, constant thereafter

// ---------------- device kernels ----------------

// CSR build without global atomic-with-return:
// block b = (chunk c = b>>1, dst-half h = b&1). LDS histogram, u16 pairs packed
// in u32 (low = even dst, high = odd dst); per-chunk count <= 6250 so no carry.
__global__ __launch_bounds__(256) void hist_kernel(const int* __restrict__ ei,
                                                   uint32_t* __restrict__ hist) {
  __shared__ uint32_t cnt[HPAIRS];  // 50 KB
  int b = blockIdx.x, c = b >> 1, h = b & 1;
  for (int i = threadIdx.x; i < HPAIRS; i += 256) cnt[i] = 0;
  __syncthreads();
  int e0 = c * CHUNK_E;
  int dlo = h * HALF;
  for (int t = threadIdx.x; t < CHUNK_E; t += 256) {
    int d = ei[EE + e0 + t];
    int dl = d - dlo;
    if ((unsigned)dl < (unsigned)HALF)
      atomicAdd(&cnt[dl >> 1], (dl & 1) ? 0x10000u : 1u);
  }
  __syncthreads();
  uint32_t* outp = hist + (size_t)c * PAIRS + (size_t)h * HPAIRS;
  for (int i = threadIdx.x; i < HPAIRS; i += 256) outp[i] = cnt[i];
}

// counts[d] = sum over chunks of hist  (replaces global-atomic count_kernel)
__global__ void counts_kernel(const uint32_t* __restrict__ hist, int* __restrict__ counts) {
  int dp = blockIdx.x * 256 + threadIdx.x;
  if (dp >= PAIRS) return;
  uint32_t lo = 0, hi = 0;
  for (int c = 0; c < CHUNKS; ++c) {
    uint32_t p = hist[(size_t)c * PAIRS + dp];
    lo += p & 0xFFFFu; hi += p >> 16;
  }
  counts[2 * dp] = (int)lo;
  counts[2 * dp + 1] = (int)hi;
}

__global__ __launch_bounds__(1024) void scan_kernel(const int* __restrict__ counts,
                                                    int* __restrict__ offsets, int n) {
  __shared__ int wsum[16];
  __shared__ int wscan[16];
  __shared__ int carry_s;
  int tid = threadIdx.x, lane = tid & 63, wid = tid >> 6;
  if (tid == 0) carry_s = 0;
  __syncthreads();
  for (int base = 0; base < n; base += 1024) {
    int i = base + tid;
    int v = (i < n) ? counts[i] : 0;
    int x = v;
    #pragma unroll
    for (int off = 1; off < 64; off <<= 1) {
      int t = __shfl_up(x, off);
      if (lane >= off) x += t;
    }
    if (lane == 63) wsum[wid] = x;
    __syncthreads();
    if (wid == 0) {
      int wv = (lane < 16) ? wsum[lane] : 0;
      #pragma unroll
      for (int off = 1; off < 16; off <<= 1) {
        int t = __shfl_up(wv, off);
        if (lane >= off) wv += t;
      }
      if (lane < 16) wscan[lane] = wv;
    }
    __syncthreads();
    int wbase = (wid == 0) ? 0 : wscan[wid - 1];
    int carry = carry_s;
    if (i < n) offsets[i] = carry + wbase + x - v;
    int total = wscan[15];
    __syncthreads();
    if (tid == 0) carry_s = carry + total;
    __syncthreads();
  }
  if (threadIdx.x == 0) offsets[n] = carry_s;
}

// base[c][d] = offsets[d] + sum_{c'<c} hist[c'][d]
__global__ void base_kernel(const uint32_t* __restrict__ hist, const int* __restrict__ offsets,
                            uint32_t* __restrict__ basearr) {
  int dp = blockIdx.x * 256 + threadIdx.x;
  if (dp >= PAIRS) return;
  uint32_t r0 = (uint32_t)offsets[2 * dp];
  uint32_t r1 = (uint32_t)offsets[2 * dp + 1];
  for (int c = 0; c < CHUNKS; ++c) {
    uint32_t p = hist[(size_t)c * PAIRS + dp];
    basearr[(size_t)c * NN + 2 * dp] = r0;
    basearr[(size_t)c * NN + 2 * dp + 1] = r1;
    r0 += p & 0xFFFFu; r1 += p >> 16;
  }
}

// rank within (chunk,dst) via cheap LDS atomic-with-return; global write is
// fire-and-forget. Order within a dst segment is arbitrary (sum is commutative).
__global__ __launch_bounds__(256) void scatter2_kernel(const int* __restrict__ ei,
                                                       const uint32_t* __restrict__ basearr,
                                                       int* __restrict__ srcs) {
  __shared__ uint32_t cnt[HPAIRS];  // 50 KB
  int b = blockIdx.x, c = b >> 1, h = b & 1;
  for (int i = threadIdx.x; i < HPAIRS; i += 256) cnt[i] = 0;
  __syncthreads();
  int e0 = c * CHUNK_E;
  int dlo = h * HALF;
  const uint32_t* baserow = basearr + (size_t)c * NN;
  for (int t = threadIdx.x; t < CHUNK_E; t += 256) {
    int s = ei[e0 + t];
    int d = ei[EE + e0 + t];
    int dl = d - dlo;
    if ((unsigned)dl < (unsigned)HALF) {
      uint32_t old = atomicAdd(&cnt[dl >> 1], (dl & 1) ? 0x10000u : 1u);
      uint32_t rank = (dl & 1) ? (old >> 16) : (old & 0xFFFFu);
      srcs[baserow[d] + rank] = s;
    }
  }
}

// C[N,64] = gather(A)[N,512] @ B[512,64]
__global__ __launch_bounds__(256) void gemm1_kernel(const float* __restrict__ A,
                                                    const float* __restrict__ B,
                                                    float* __restrict__ C,
                                                    const int* __restrict__ gather, int n) {
  __shared__ float As[32][68];
  __shared__ float Bs[32][68];
  int t = threadIdx.x;
  int m0 = blockIdx.x * 64;
  int tr = t >> 4, tc = t & 15;
  float acc[4][4] = {};
  for (int k0 = 0; k0 < 512; k0 += 32) {
    #pragma unroll
    for (int q = 0; q < 2; ++q) {
      int f = t + q * 256;
      int r = f >> 3, kq = f & 7;
      int row = m0 + r; row = (row < n) ? row : (n - 1);
      int g = gather ? gather[row] : row;
      const float4 av = *(const float4*)(A + (size_t)g * 512 + k0 + kq * 4);
      As[kq * 4 + 0][r] = av.x; As[kq * 4 + 1][r] = av.y;
      As[kq * 4 + 2][r] = av.z; As[kq * 4 + 3][r] = av.w;
    }
    #pragma unroll
    for (int q = 0; q < 2; ++q) {
      int f = t + q * 256;
      int kk = f >> 4, cq = f & 15;
      const float4 bv = *(const float4*)(B + (size_t)(k0 + kk) * 64 + cq * 4);
      *(float4*)(&Bs[kk][cq * 4]) = bv;
    }
    __syncthreads();
    #pragma unroll
    for (int kk = 0; kk < 32; ++kk) {
      float a[4], b[4];
      #pragma unroll
      for (int i = 0; i < 4; i++) a[i] = As[kk][tr * 4 + i];
      #pragma unroll
      for (int j = 0; j < 4; j++) b[j] = Bs[kk][tc * 4 + j];
      #pragma unroll
      for (int i = 0; i < 4; i++)
        #pragma unroll
        for (int j = 0; j < 4; j++) acc[i][j] += a[i] * b[j];
    }
    __syncthreads();
  }
  #pragma unroll
  for (int i = 0; i < 4; i++) {
    int row = m0 + tr * 4 + i;
    if (row < n) {
      float4 v = {acc[i][0], acc[i][1], acc[i][2], acc[i][3]};
      *(float4*)(C + (size_t)row * 64 + tc * 4) = v;
    }
  }
}

// per-node s = xw . a_src ; d = xw . a_dst  (one wave per node)
__global__ void dots_kernel(const float* __restrict__ xw, const float* __restrict__ a_src,
                            const float* __restrict__ a_dst, float* __restrict__ s,
                            float* __restrict__ d, int n) {
  int w = (blockIdx.x * blockDim.x + threadIdx.x) >> 6;
  int lane = threadIdx.x & 63;
  if (w >= n) return;
  float v = xw[(size_t)w * 64 + lane];
  float vs = v * a_src[lane], vd = v * a_dst[lane];
  #pragma unroll
  for (int off = 32; off; off >>= 1) {
    vs += __shfl_down(vs, off);
    vd += __shfl_down(vd, off);
  }
  if (lane == 0) { s[w] = vs; d[w] = vd; }
}

// per-dst segment softmax + weighted aggregation + ELU (one wave per dst)
__global__ __launch_bounds__(256) void gat_kernel(const int* __restrict__ offs,
                                                  const int* __restrict__ srcs,
                                                  const float* __restrict__ s,
                                                  const float* __restrict__ dvec,
                                                  const float* __restrict__ xw,
                                                  float* __restrict__ h, int n) {
  int w = (blockIdx.x * blockDim.x + threadIdx.x) >> 6;
  int lane = threadIdx.x & 63;
  if (w >= n) return;
  int start = offs[w], end = offs[w + 1];
  float dd = dvec[w];
  float m = -INFINITY;
  for (int j = start + lane; j < end; j += 64) {
    float e = s[srcs[j]] + dd;
    e = e > 0.f ? e : 0.2f * e;
    m = fmaxf(m, e);
  }
  #pragma unroll
  for (int off = 32; off; off >>= 1) m = fmaxf(m, __shfl_xor(m, off));
  float sum = 0.f;
  for (int j = start + lane; j < end; j += 64) {
    float e = s[srcs[j]] + dd;
    e = e > 0.f ? e : 0.2f * e;
    sum += __expf(e - m);
  }
  #pragma unroll
  for (int off = 32; off; off >>= 1) sum += __shfl_xor(sum, off);
  float inv = 1.0f / (sum + 1e-16f);
  float acc = 0.f;
  for (int j = start; j < end; ++j) {
    int sj = srcs[j];
    float e = s[sj] + dd;
    e = e > 0.f ? e : 0.2f * e;
    float alpha = __expf(e - m) * inv;
    acc += alpha * xw[(size_t)sj * 64 + lane];
  }
  h[(size_t)w * 64 + lane] = acc > 0.f ? acc : expm1f(acc);
}

// h2[N,32] = h1[N,64] @ W2[64,32]
__global__ void gemm2_kernel(const float* __restrict__ h1, const float* __restrict__ W2,
                             float* __restrict__ h2, int n) {
  int id = blockIdx.x * 256 + threadIdx.x;
  if (id >= n * 32) return;
  int i = id >> 5, c = id & 31;
  float sacc = 0.f;
  #pragma unroll
  for (int k = 0; k < 64; k++) sacc += h1[(size_t)i * 64 + k] * W2[k * 32 + c];
  h2[id] = sacc;
}

// xw3[N,64] = h2[N,32] @ W2^T  (xw3[i,c] = sum_j h2[i,j]*W2[c,j])
__global__ void gemm3_kernel(const float* __restrict__ h2, const float* __restrict__ W2,
                             float* __restrict__ xw3, int n) {
  int id = blockIdx.x * 256 + threadIdx.x;
  if (id >= n * 64) return;
  int i = id >> 6, c = id & 63;
  float sacc = 0.f;
  #pragma unroll
  for (int j = 0; j < 32; j++) sacc += h2[(size_t)i * 32 + j] * W2[c * 32 + j];
  xw3[id] = sacc;
}

// h4[N,512] = h3[N,64] @ W1^T ; writes two copies
__global__ __launch_bounds__(256) void gemm4_kernel(const float* __restrict__ A,
                                                    const float* __restrict__ W1,
                                                    float* __restrict__ C0,
                                                    float* __restrict__ C1, int n) {
  __shared__ float As[64][68];
  __shared__ float Bs[64][68];
  int t = threadIdx.x;
  int m0 = blockIdx.x * 64;
  int o0 = blockIdx.y * 64;
  int tr = t >> 4, tc = t & 15;
  #pragma unroll
  for (int q = 0; q < 4; ++q) {
    int f = t + q * 256;
    int r = f >> 4, cq = f & 15;
    int row = m0 + r; row = (row < n) ? row : (n - 1);
    const float4 av = *(const float4*)(A + (size_t)row * 64 + cq * 4);
    As[cq * 4 + 0][r] = av.x; As[cq * 4 + 1][r] = av.y;
    As[cq * 4 + 2][r] = av.z; As[cq * 4 + 3][r] = av.w;
  }
  #pragma unroll
  for (int q = 0; q < 4; ++q) {
    int f = t + q * 256;
    int o = f >> 4, cq = f & 15;
    const float4 wv = *(const float4*)(W1 + (size_t)(o0 + o) * 64 + cq * 4);
    Bs[cq * 4 + 0][o] = wv.x; Bs[cq * 4 + 1][o] = wv.y;
    Bs[cq * 4 + 2][o] = wv.z; Bs[cq * 4 + 3][o] = wv.w;
  }
  __syncthreads();
  float acc[4][4] = {};
  #pragma unroll
  for (int kk = 0; kk < 64; ++kk) {
    float a[4], b[4];
    #pragma unroll
    for (int i = 0; i < 4; i++) a[i] = As[kk][tr * 4 + i];
    #pragma unroll
    for (int j = 0; j < 4; j++) b[j] = Bs[kk][tc * 4 + j];
    #pragma unroll
    for (int i = 0; i < 4; i++)
      #pragma unroll
      for (int j = 0; j < 4; j++) acc[i][j] += a[i] * b[j];
  }
  #pragma unroll
  for (int i = 0; i < 4; i++) {
    int row = m0 + tr * 4 + i;
    if (row < n) {
      float4 v = {acc[i][0], acc[i][1], acc[i][2], acc[i][3]};
      *(float4*)(C0 + (size_t)row * 512 + o0 + tc * 4) = v;
      *(float4*)(C1 + (size_t)row * 512 + o0 + tc * 4) = v;
    }
  }
}

__global__ void colsum_kernel(const float* __restrict__ h2, float* __restrict__ acc, int n) {
  int c = threadIdx.x & 31;
  int rg = (blockIdx.x << 3) + (threadIdx.x >> 5);
  float sloc = 0.f;
  for (int r = rg; r < n; r += 2048) sloc += h2[(size_t)r * 32 + c];
  atomicAdd(&acc[c], sloc);
}

__global__ void finalize_kernel(const float* __restrict__ acc, float* __restrict__ outp, int n) {
  int c = threadIdx.x;
  if (c < 32) {
    float mval = acc[c] / (float)n;
    outp[c] = 1.0f / (1.0f + __expf(-mval));
  }
}

// ---------------- launch ----------------
extern "C" void kernel_launch(void* const* d_in, const int* in_sizes, int n_in,
                              void* d_out, int out_size, void* d_ws, size_t ws_size,
                              hipStream_t stream) {
  const float* features = (const float*)d_in[0];
  const int*   ei       = (const int*)d_in[1];
  const float* W1       = (const float*)d_in[2];
  const float* a1s      = (const float*)d_in[3];
  const float* a1d      = (const float*)d_in[4];
  const float* W2       = (const float*)d_in[5];
  const float* a3s      = (const float*)d_in[6];
  const float* a3d      = (const float*)d_in[7];
  float* out = (float*)d_out;

  const size_t NOUT = (size_t)NN * 32;   // 1,600,000
  const size_t NH4  = (size_t)NN * 512;  // 25,600,000
  const size_t OFF1 = NOUT;
  const size_t OFF2 = OFF1 + NH4;
  const size_t OFF3 = OFF2 + NH4;
  const size_t OFF4 = OFF3 + NOUT;
  const size_t OFF5 = OFF4 + NH4;
  const size_t OFF6 = OFF5 + NH4;

  char* w = (char*)d_ws;
  size_t o = 0;
  auto alloc = [&](size_t bytes) -> void* {
    void* p = w + o;
    o = (o + bytes + 255) & ~(size_t)255;
    return p;
  };
  int*      d_perm  = (int*)alloc((size_t)NN * 4);
  int*      counts  = (int*)alloc((size_t)NN * 4);
  int*      offsets = (int*)alloc((size_t)(NN + 1) * 4);
  int*      srcs    = (int*)alloc((size_t)EE * 4);
  uint32_t* hist    = (uint32_t*)alloc((size_t)CHUNKS * PAIRS * 4);  // 12.8 MB
  uint32_t* basearr = (uint32_t*)alloc((size_t)CHUNKS * NN * 4);     // 25.6 MB
  float*    xw      = (float*)alloc((size_t)NN * 64 * 4);
  float*    hbuf    = (float*)alloc((size_t)NN * 64 * 4);
  float*    sbuf    = (float*)alloc((size_t)NN * 4);
  float*    dbuf    = (float*)alloc((size_t)NN * 4);
  float*    accbuf  = (float*)alloc(32 * 4);

  // g_perm.perm is a load-time constant; this is the same H2D copy every call.
  hipMemcpyAsync(d_perm, g_perm.perm, (size_t)NN * 4, hipMemcpyHostToDevice, stream);
  hipMemsetAsync(accbuf, 0, 32 * 4, stream);

  // CSR build: chunked counting sort, no global atomic-with-return anywhere.
  hist_kernel<<<CHUNKS * 2, 256, 0, stream>>>(ei, hist);
  counts_kernel<<<(PAIRS + 255) / 256, 256, 0, stream>>>(hist, counts);
  scan_kernel<<<1, 1024, 0, stream>>>(counts, offsets, NN);
  base_kernel<<<(PAIRS + 255) / 256, 256, 0, stream>>>(hist, offsets, basearr);
  scatter2_kernel<<<CHUNKS * 2, 256, 0, stream>>>(ei, basearr, srcs);

  const int rowBlocks = (NN + 63) / 64;        // 782
  const int nodeWaveBlocks = (NN * 64 + 255) / 256;  // 12500

  for (int b = 0; b < 2; ++b) {
    const int* g = b ? d_perm : nullptr;
    float* h2out = out + (b ? OFF3 : 0);
    float* h4a   = out + (b ? OFF4 : OFF1);
    float* h4b   = out + (b ? OFF5 : OFF2);

    gemm1_kernel<<<rowBlocks, 256, 0, stream>>>(features, W1, xw, g, NN);
    dots_kernel<<<nodeWaveBlocks, 256, 0, stream>>>(xw, a1s, a1d, sbuf, dbuf, NN);
    gat_kernel<<<nodeWaveBlocks, 256, 0, stream>>>(offsets, srcs, sbuf, dbuf, xw, hbuf, NN);
    gemm2_kernel<<<(NN * 32 + 255) / 256, 256, 0, stream>>>(hbuf, W2, h2out, NN);
    gemm3_kernel<<<(NN * 64 + 255) / 256, 256, 0, stream>>>(h2out, W2, xw, NN);
    dots_kernel<<<nodeWaveBlocks, 256, 0, stream>>>(xw, a3s, a3d, sbuf, dbuf, NN);
    gat_kernel<<<nodeWaveBlocks, 256, 0, stream>>>(offsets, srcs, sbuf, dbuf, xw, hbuf, NN);
    gemm4_kernel<<<dim3(rowBlocks, 8), 256, 0, stream>>>(hbuf, W1, h4a, h4b, NN);
  }

  colsum_kernel<<<256, 256, 0, stream>>>(out, accbuf, NN);
  finalize_kernel<<<1, 64, 0, stream>>>(accbuf, out + OFF6, NN);
}